// Round 19
// baseline (399.166 us; speedup 1.0000x reference)
//
#include <hip/hip_runtime.h>
#include <math.h>

// Problem constants
constexpr int NB = 2, NL = 2048, ND = 1024, NH = 4;
constexpr int NCHK = 64;            // L / 32
constexpr int NBL = NB * NL;        // 4096
#define BLDSZ (NB * NL * ND)        // 4194304

// per-chunk packed operand file (shorts): [W 8192 | Q 8192 | Kt 8192 | Ut 8192 | At 1024 | pad]
constexpr int OPS_CH = 36864;       // shorts = 72 KB
// staged subset per scan wave: W 16 | Q 16 | Kt 16 | Ut-slice 2 | At 2 = 52 KB
constexpr int STG_CH = 26624;       // shorts = 52 KB

// ---- static device scratch ----
__device__ float g_v[BLDSZ];
__device__ float g_delta[BLDSZ];  // (B,L,H,DV)
__device__ float g_fs[BLDSZ];
__device__ float g_fl[BLDSZ];
__device__ float g_xw1[BLDSZ];    // x @ W1[:1024,:]
__device__ float g_beta[NBL * NH];
__device__ unsigned short g_qlb[BLDSZ];   // qkv GEMM outputs, bf16 (pre-conv)
__device__ unsigned short g_klb[BLDSZ];
__device__ unsigned short g_vlb[BLDSZ];
__device__ unsigned short g_ops[(size_t)8 * 64 * OPS_CH];  // 37.7 MB
__device__ unsigned short g_xb[BLDSZ];                      // x bf16
__device__ unsigned short g_omixb[BLDSZ];                   // mixed output bf16
__device__ unsigned short g_btw[5 * 1024 * 1024];           // 5 weights, [n][k] bf16

__device__ __forceinline__ float sigmoidf(float x) { return 1.f / (1.f + expf(-x)); }

__device__ __forceinline__ unsigned short f2bf(float f) {
  union { float f; unsigned int u; } v; v.f = f;
  unsigned int r = v.u + 0x7FFFu + ((v.u >> 16) & 1u);   // RNE
  return (unsigned short)(r >> 16);
}
__device__ __forceinline__ float bf2f(unsigned int bits16) {
  union { unsigned int u; float f; } v; v.u = bits16 << 16; return v.f;
}
__device__ __forceinline__ unsigned int packbf(float a, float b) {
  return (unsigned int)f2bf(a) | ((unsigned int)f2bf(b) << 16);
}

typedef __attribute__((ext_vector_type(8))) short short8v;   // 8 bf16 (4 VGPR)
typedef __attribute__((ext_vector_type(16))) float f32x16;   // MFMA 32x32 accum

__device__ __forceinline__ unsigned int cvtpk(float lo, float hi) {
  unsigned int r;
  asm("v_cvt_pk_bf16_f32 %0, %1, %2" : "=v"(r) : "v"(lo), "v"(hi));
  return r;
}

// C-layout f32x16 (col=l31, row=(e&3)+8*(e>>2)+4*lhi) -> two K-slice B-frags
__device__ __forceinline__ void mkfrag(const f32x16 v, short8v& fb0, short8v& fb1) {
  unsigned int P0 = cvtpk(v[0], v[1]),   P1 = cvtpk(v[2], v[3]);
  unsigned int P2 = cvtpk(v[4], v[5]),   P3 = cvtpk(v[6], v[7]);
  unsigned int P4 = cvtpk(v[8], v[9]),   P5 = cvtpk(v[10], v[11]);
  unsigned int P6 = cvtpk(v[12], v[13]), P7 = cvtpk(v[14], v[15]);
  asm("v_permlane32_swap_b32 %0, %1" : "+v"(P0), "+v"(P2));
  asm("v_permlane32_swap_b32 %0, %1" : "+v"(P1), "+v"(P3));
  asm("v_permlane32_swap_b32 %0, %1" : "+v"(P4), "+v"(P6));
  asm("v_permlane32_swap_b32 %0, %1" : "+v"(P5), "+v"(P7));
  unsigned int f0[4] = {P0, P1, P2, P3}, f1[4] = {P4, P5, P6, P7};
  fb0 = *(short8v*)f0; fb1 = *(short8v*)f1;
}

#define GLL16(SRC, DST)                                                                    \
  __builtin_amdgcn_global_load_lds(                                                        \
      (const __attribute__((address_space(1))) unsigned int*)(SRC),                        \
      (__attribute__((address_space(3))) unsigned int*)(DST), 16, 0, 0)

// ---- 128x128 / BK=64 GEMM core: both-sides row-XOR swizzle ----
__device__ __forceinline__ void gemm128_core(const unsigned short* __restrict__ A,
                                             const unsigned short* __restrict__ Bt,
                                             int m0, int n0, int t,
                                             unsigned short* As, unsigned short* Bs,
                                             f32x16 acc[2][2]) {
  const int w = t >> 6, lane = t & 63, l31 = lane & 31, lhi = lane >> 5;
  const int wm = (w & 1) * 64, wn = (w >> 1) * 64;
#pragma unroll
  for (int mt = 0; mt < 2; ++mt)
#pragma unroll
    for (int nt = 0; nt < 2; ++nt)
#pragma unroll
      for (int e = 0; e < 16; ++e) acc[mt][nt][e] = 0.f;

  for (int k0 = 0; k0 < 1024; k0 += 64) {
#pragma unroll
    for (int i = 0; i < 4; ++i) {
      int sl = i * 4 + w;
      int srow = sl * 8 + (lane >> 3);
      int gc = (((lane & 7) ^ (srow & 7))) * 8;
      GLL16(A + (size_t)(m0 + srow) * 1024 + k0 + gc, &As[sl * 512]);
      GLL16(Bt + (size_t)(n0 + srow) * 1024 + k0 + gc, &Bs[sl * 512]);
    }
    __syncthreads();
#pragma unroll
    for (int ksl = 0; ksl < 4; ++ksl) {
      int kb = ksl * 2 + lhi;
      short8v af[2], bf[2];
#pragma unroll
      for (int mt = 0; mt < 2; ++mt) {
        int row = wm + mt * 32 + l31;
        af[mt] = *(const short8v*)&As[row * 64 + ((kb ^ (row & 7)) * 8)];
      }
#pragma unroll
      for (int nt = 0; nt < 2; ++nt) {
        int row = wn + nt * 32 + l31;
        bf[nt] = *(const short8v*)&Bs[row * 64 + ((kb ^ (row & 7)) * 8)];
      }
#pragma unroll
      for (int mt = 0; mt < 2; ++mt)
#pragma unroll
        for (int nt = 0; nt < 2; ++nt)
          acc[mt][nt] = __builtin_amdgcn_mfma_f32_32x32x16_bf16(af[mt], bf[nt], acc[mt][nt], 0, 0, 0);
    }
    __syncthreads();
  }
}

// ================= pack_all: x->bf16 (0-2047) + 5 weights (2048-3327) + beta (3328-7423) =================
__global__ __launch_bounds__(256) void pack_all_kernel(const float* __restrict__ x,
                                                       const float* __restrict__ Wq,
                                                       const float* __restrict__ Wk,
                                                       const float* __restrict__ Wv,
                                                       const float* __restrict__ W1,
                                                       const float* __restrict__ Wo,
                                                       const float* __restrict__ Wb) {
  __shared__ float tile[64][65];
  int blk = blockIdx.x, t = threadIdx.x;
  if (blk < 2048) {
    int i8 = blk * 256 + t;
    const float* p = x + (size_t)i8 * 8;
    float4 a = *(const float4*)p;
    float4 b = *(const float4*)(p + 4);
    uint4 v;
    v.x = packbf(a.x, a.y); v.y = packbf(a.z, a.w);
    v.z = packbf(b.x, b.y); v.w = packbf(b.z, b.w);
    *(uint4*)&g_xb[(size_t)i8 * 8] = v;
    return;
  }
  if (blk < 3328) {
    int sel = (blk - 2048) >> 8, wb = (blk - 2048) & 255;
    const float* W = (sel == 0) ? Wq : (sel == 1) ? Wk : (sel == 2) ? Wv : (sel == 3) ? W1 : Wo;
    int bx = wb & 15, by = wb >> 4;
    int n0 = bx * 64, k0 = by * 64;
#pragma unroll
    for (int i = 0; i < 4; ++i) {
      int id = t + i * 256;
      int r = id >> 4, c4 = (id & 15) * 4;
      float4 v = *(const float4*)&W[(size_t)(k0 + r) * 1024 + n0 + c4];
      tile[r][c4 + 0] = v.x; tile[r][c4 + 1] = v.y; tile[r][c4 + 2] = v.z; tile[r][c4 + 3] = v.w;
    }
    __syncthreads();
    unsigned int* out = (unsigned int*)g_btw + (size_t)sel * 524288;
#pragma unroll
    for (int i = 0; i < 8; ++i) {
      int id = t + i * 256;
      int nn = id >> 5, ku = id & 31;
      out[(size_t)(n0 + nn) * 512 + (k0 >> 1) + ku] = packbf(tile[2 * ku][nn], tile[2 * ku + 1][nn]);
    }
    return;
  }
  // beta = sigmoid(x @ Wb)
  int bl = blk - 3328;
  int h = t >> 6, lane = t & 63;
  const float* xr = x + (size_t)bl * ND;
  float acc = 0.f;
  for (int d = lane; d < ND; d += 64) acc += xr[d] * Wb[d * 4 + h];
#pragma unroll
  for (int off = 32; off; off >>= 1) acc += __shfl_xor(acc, off);
  if (lane == 0) g_beta[bl * 4 + h] = sigmoidf(acc);
}

// ================= QKV GEMM: 3 GEMMs in one launch (grid 768), XCD-swizzled tiles =================
__global__ __launch_bounds__(256) void qkv_gemm_kernel() {
  __shared__ unsigned short As[128 * 64];
  __shared__ unsigned short Bs[128 * 64];
  const int sel = blockIdx.x >> 8;
  const int hb0 = blockIdx.x & 255;
  const int hb = (hb0 & 7) * 32 + (hb0 >> 3);    // XCD-contiguous by-ranges
  const unsigned short* Bt = g_btw + (size_t)sel * 1024 * 1024;
  unsigned short* C = (sel == 0) ? g_qlb : (sel == 1) ? g_klb : g_vlb;
  const int m0 = (hb >> 3) * 128, n0 = (hb & 7) * 128;
  const int t = threadIdx.x;
  const int w = t >> 6, lane = t & 63, l31 = lane & 31, lhi = lane >> 5;
  const int wm = (w & 1) * 64, wn = (w >> 1) * 64;
  f32x16 acc[2][2];
  gemm128_core(g_xb, Bt, m0, n0, t, As, Bs, acc);
#pragma unroll
  for (int mt = 0; mt < 2; ++mt)
#pragma unroll
    for (int nt = 0; nt < 2; ++nt) {
      int col = n0 + wn + nt * 32 + l31;
#pragma unroll
      for (int e = 0; e < 16; ++e) {
        int row = m0 + wm + mt * 32 + (e & 3) + 8 * (e >> 2) + 4 * lhi;
        C[(size_t)row * 1024 + col] = f2bf(acc[mt][nt][e]);
      }
    }
}

// ================= final GEMM: out = omixb @ Wo^T (BK=64 swizzled, XCD tiles) =================
__global__ __launch_bounds__(256) void hgemm_out_kernel(float* __restrict__ Cext) {
  __shared__ unsigned short As[128 * 64];
  __shared__ unsigned short Bs[128 * 64];
  const int hb = (blockIdx.x & 7) * 32 + (blockIdx.x >> 3);
  const int m0 = (hb >> 3) * 128, n0 = (hb & 7) * 128;
  const int t = threadIdx.x;
  const int w = t >> 6, lane = t & 63, l31 = lane & 31, lhi = lane >> 5;
  const int wm = (w & 1) * 64, wn = (w >> 1) * 64;
  f32x16 acc[2][2];
  gemm128_core(g_omixb, g_btw + (size_t)4 * 1024 * 1024, m0, n0, t, As, Bs, acc);
#pragma unroll
  for (int mt = 0; mt < 2; ++mt)
#pragma unroll
    for (int nt = 0; nt < 2; ++nt) {
      int col = n0 + wn + nt * 32 + l31;
#pragma unroll
      for (int e = 0; e < 16; ++e) {
        int row = m0 + wm + mt * 32 + (e & 3) + 8 * (e >> 2) + 4 * lhi;
        Cext[(size_t)row * 1024 + col] = acc[mt][nt][e];
      }
    }
}

// ================= delta-rule chunk prep: fused q/k/v conv+silu, MFMA attn/A, fast T-inverse =================
__global__ __launch_bounds__(256) void delta_prep_kernel(const float* __restrict__ cq,
                                                         const float* __restrict__ ck,
                                                         const float* __restrict__ cv) {
  __shared__ float X[32][260];
  __shared__ float Y[32][260];
  __shared__ float Am[32][33];
  __shared__ float Tm[32][33];
  __shared__ float bet[32];
  int blk = blockIdx.x;                  // cblk = (b*4+h)*64 + n
  int n = blk & 63, h = (blk >> 6) & 3, b = blk >> 8;
  int t = threadIdx.x;
  size_t rowbase = (size_t)(b * NL + n * 32);
  size_t obase = (size_t)blk * OPS_CH;
  const int st_ = t >> 5, j_ = (t >> 4) & 1, lh_ = (t >> 3) & 1, e_ = t & 7;
  const int l31_ = t & 31;

  float vv[32];   // v (post conv+silu) for this thread's column, rows 0..31

  // ---- fused causal conv(K=4)+SiLU for q,k,v from bf16 GEMM outputs; thread t owns head-col t ----
  {
    const int hcol = h * 256 + t;
    const unsigned short* qp = g_qlb + hcol;
    const unsigned short* kp = g_klb + hcol;
    const unsigned short* vp = g_vlb + hcol;
    float wq0 = cq[hcol * 4 + 0], wq1 = cq[hcol * 4 + 1], wq2 = cq[hcol * 4 + 2], wq3 = cq[hcol * 4 + 3];
    float wk0 = ck[hcol * 4 + 0], wk1 = ck[hcol * 4 + 1], wk2 = ck[hcol * 4 + 2], wk3 = ck[hcol * 4 + 3];
    float wv0 = cv[hcol * 4 + 0], wv1 = cv[hcol * 4 + 1], wv2 = cv[hcol * 4 + 2], wv3 = cv[hcol * 4 + 3];
    float qa = 0.f, qb_ = 0.f, qc = 0.f, ka = 0.f, kb_ = 0.f, kc = 0.f;
    float va = 0.f, vb_ = 0.f, vc = 0.f;
    if (n > 0) {
      qa = bf2f(qp[(rowbase - 3) * 1024]); qb_ = bf2f(qp[(rowbase - 2) * 1024]); qc = bf2f(qp[(rowbase - 1) * 1024]);
      ka = bf2f(kp[(rowbase - 3) * 1024]); kb_ = bf2f(kp[(rowbase - 2) * 1024]); kc = bf2f(kp[(rowbase - 1) * 1024]);
      va = bf2f(vp[(rowbase - 3) * 1024]); vb_ = bf2f(vp[(rowbase - 2) * 1024]); vc = bf2f(vp[(rowbase - 1) * 1024]);
    }
#pragma unroll 4
    for (int r = 0; r < 32; ++r) {
      float qd = bf2f(qp[(rowbase + r) * 1024]);
      float kd = bf2f(kp[(rowbase + r) * 1024]);
      float vd = bf2f(vp[(rowbase + r) * 1024]);
      float aq = wq3 * qd + wq2 * qc + wq1 * qb_ + wq0 * qa;
      float ak = wk3 * kd + wk2 * kc + wk1 * kb_ + wk0 * ka;
      float av = wv3 * vd + wv2 * vc + wv1 * vb_ + wv0 * va;
      X[r][t] = aq * sigmoidf(aq);
      Y[r][t] = ak * sigmoidf(ak);
      float vo = av * sigmoidf(av);
      vv[r] = vo;
      g_v[(rowbase + r) * 1024 + hcol] = vo;
      qa = qb_; qb_ = qc; qc = qd;
      ka = kb_; kb_ = kc; kc = kd;
      va = vb_; vb_ = vc; vc = vd;
    }
  }
  if (t < 32) bet[t] = g_beta[(rowbase + t) * 4 + h];
  __syncthreads();

  // row l2norm of q,k
  {
    int wv_ = t >> 6, lane = t & 63;
    int r = wv_ * 8 + (lane >> 3), sub = lane & 7;
    float sq = 0.f, sk = 0.f;
#pragma unroll
    for (int m4 = 0; m4 < 8; ++m4) {
      float4 a = *(const float4*)&X[r][sub * 32 + m4 * 4];
      float4 bb = *(const float4*)&Y[r][sub * 32 + m4 * 4];
      sq += a.x * a.x + a.y * a.y + a.z * a.z + a.w * a.w;
      sk += bb.x * bb.x + bb.y * bb.y + bb.z * bb.z + bb.w * bb.w;
    }
    sq += __shfl_xor(sq, 1); sq += __shfl_xor(sq, 2); sq += __shfl_xor(sq, 4);
    sk += __shfl_xor(sk, 1); sk += __shfl_xor(sk, 2); sk += __shfl_xor(sk, 4);
    float rq = rsqrtf(sq + 1e-6f), rk = rsqrtf(sk + 1e-6f);
#pragma unroll
    for (int m4 = 0; m4 < 8; ++m4) {
      float4 a = *(const float4*)&X[r][sub * 32 + m4 * 4];
      a.x *= rq; a.y *= rq; a.z *= rq; a.w *= rq;
      *(float4*)&X[r][sub * 32 + m4 * 4] = a;
      float4 bb = *(const float4*)&Y[r][sub * 32 + m4 * 4];
      bb.x *= rk; bb.y *= rk; bb.z *= rk; bb.w *= rk;
      *(float4*)&Y[r][sub * 32 + m4 * 4] = bb;
    }
  }
  __syncthreads();

  // attn = incl_lower(qn kn^T) via MFMA (wave 0) -> At region
  if (t < 64) {
    const int al = t & 31, ah = t >> 5;
    f32x16 Cat;
#pragma unroll
    for (int e = 0; e < 16; ++e) Cat[e] = 0.f;
#pragma unroll
    for (int st = 0; st < 16; ++st) {
      int kb = st * 16 + ah * 8;
      float4 a0 = *(const float4*)&X[al][kb], a1 = *(const float4*)&X[al][kb + 4];
      float4 b0 = *(const float4*)&Y[al][kb], b1 = *(const float4*)&Y[al][kb + 4];
      unsigned int af[4] = {cvtpk(a0.x, a0.y), cvtpk(a0.z, a0.w), cvtpk(a1.x, a1.y), cvtpk(a1.z, a1.w)};
      unsigned int bf_[4] = {cvtpk(b0.x, b0.y), cvtpk(b0.z, b0.w), cvtpk(b1.x, b1.y), cvtpk(b1.z, b1.w)};
      Cat = __builtin_amdgcn_mfma_f32_32x32x16_bf16(*(short8v*)af, *(short8v*)bf_, Cat, 0, 0, 0);
    }
#pragma unroll
    for (int e = 0; e < 16; ++e) {
      int row = (e & 3) + 8 * (e >> 2) + 4 * ah, col = al;
      float v = (col <= row) ? Cat[e] : 0.f;
      g_ops[obase + 32768 + (size_t)(((col >> 4) * 64) + ((col >> 3) & 1) * 32 + row) * 8 + (col & 7)] = f2bf(v);
    }
  }

  // qn -> Q region; kn -> Kt region
  {
    size_t qb = obase + 8192 + (size_t)(((st_ * 2 + j_) * 64) + lh_ * 32) * 8 + e_;
#pragma unroll 8
    for (int r = 0; r < 32; ++r)
      g_ops[qb + r * 8] = f2bf(X[r][t]);
#pragma unroll
    for (int j = 0; j < 2; ++j)
#pragma unroll
      for (int lh = 0; lh < 2; ++lh) {
        int kr0 = j * 16 + lh * 8;
        uint4 v;
        v.x = packbf(Y[kr0 + 0][t], Y[kr0 + 1][t]);
        v.y = packbf(Y[kr0 + 2][t], Y[kr0 + 3][t]);
        v.z = packbf(Y[kr0 + 4][t], Y[kr0 + 5][t]);
        v.w = packbf(Y[kr0 + 6][t], Y[kr0 + 7][t]);
        *(uint4*)&g_ops[obase + 16384 + (size_t)(((st_ * 2 + j) * 64) + lh * 32 + l31_) * 8] = v;
      }
  }
  __syncthreads();

  // X <- k_beta
#pragma unroll
  for (int i = 0; i < 8; ++i) {
    int j = t + i * 256;
    int r = j >> 6, d4 = (j & 63) << 2;
    float be = bet[r];
    float4 bb = *(const float4*)&Y[r][d4];
    bb.x *= be; bb.y *= be; bb.z *= be; bb.w *= be;
    *(float4*)&X[r][d4] = bb;
  }
  __syncthreads();

  // A = strict_lower(kb kn^T) via MFMA (wave 0) -> Am (fp32 LDS, lower only)
  if (t < 64) {
    const int al = t & 31, ah = t >> 5;
    f32x16 Cam;
#pragma unroll
    for (int e = 0; e < 16; ++e) Cam[e] = 0.f;
#pragma unroll
    for (int st = 0; st < 16; ++st) {
      int kb = st * 16 + ah * 8;
      float4 a0 = *(const float4*)&X[al][kb], a1 = *(const float4*)&X[al][kb + 4];
      float4 b0 = *(const float4*)&Y[al][kb], b1 = *(const float4*)&Y[al][kb + 4];
      unsigned int af[4] = {cvtpk(a0.x, a0.y), cvtpk(a0.z, a0.w), cvtpk(a1.x, a1.y), cvtpk(a1.z, a1.w)};
      unsigned int bf_[4] = {cvtpk(b0.x, b0.y), cvtpk(b0.z, b0.w), cvtpk(b1.x, b1.y), cvtpk(b1.z, b1.w)};
      Cam = __builtin_amdgcn_mfma_f32_32x32x16_bf16(*(short8v*)af, *(short8v*)bf_, Cam, 0, 0, 0);
    }
#pragma unroll
    for (int e = 0; e < 16; ++e) {
      int row = (e & 3) + 8 * (e >> 2) + 4 * ah, col = al;
      if (col < row) Am[row][col] = Cam[e];
    }
  }
  __syncthreads();

  // T = (I+A)^-1 forward substitution — fully-unrolled, exec-uniform
  if (t < 32) {
    const int j = t;
#pragma unroll
    for (int i = 0; i < 32; ++i) {
      float a = (i == j) ? 1.f : 0.f;
#pragma unroll
      for (int m = 0; m < i; ++m) {
        float p = Am[i][m] * Tm[m][j];
        a -= (m >= j) ? p : 0.f;
      }
      Tm[i][j] = a;
    }
  }
  __syncthreads();

  // w = T @ kb -> W region
  {
    float acc[32];
#pragma unroll
    for (int r = 0; r < 32; ++r) acc[r] = 0.f;
#pragma unroll
    for (int m = 0; m < 32; ++m) {
      float xv = X[m][t];
#pragma unroll
      for (int r = m; r < 32; ++r) acc[r] += Tm[r][m] * xv;
    }
    size_t wb = obase + (size_t)(((st_ * 2 + j_) * 64) + lh_ * 32) * 8 + e_;
#pragma unroll 8
    for (int r = 0; r < 32; ++r)
      g_ops[wb + r * 8] = f2bf(acc[r]);
  }
  // Y <- v*beta (from registers, no global read)
  __syncthreads();
#pragma unroll
  for (int r = 0; r < 32; ++r)
    Y[r][t] = vv[r] * bet[r];
  __syncthreads();

  // u = T @ vb -> Ut region
  {
    float acc[32];
#pragma unroll
    for (int r = 0; r < 32; ++r) acc[r] = 0.f;
#pragma unroll
    for (int m = 0; m < 32; ++m) {
      float yv = Y[m][t];
#pragma unroll
      for (int r = m; r < 32; ++r) acc[r] += Tm[r][m] * yv;
    }
    int q = t >> 5;
#pragma unroll
    for (int g = 0; g < 4; ++g)
#pragma unroll
      for (int lh = 0; lh < 2; ++lh) {
        int kr0 = 8 * g + 4 * lh;
        uint2 v;
        v.x = packbf(acc[kr0 + 0], acc[kr0 + 1]);
        v.y = packbf(acc[kr0 + 2], acc[kr0 + 3]);
        *(uint2*)&g_ops[obase + 24576 + (size_t)(((q * 4 + g) * 64) + lh * 32 + l31_) * 4] = v;
      }
  }
}

// ================= MEGA: scan (0-63) + fir_long (64-575) + fir_short (576-4671) + xw1 (4672-4927) =================
__global__ __launch_bounds__(256, 1) void scan_fir_kernel(const float* __restrict__ firl,
                                                          const float* __restrict__ firs) {
  __shared__ __align__(16) unsigned char smem[2 * STG_CH * 2];  // 104 KB
  const int blk = blockIdx.x;
  const int t = threadIdx.x;

  if (blk < 64) {
    if (t >= 64) return;   // scan path: wave 0 only, no barriers
    unsigned short (*buf)[STG_CH] = (unsigned short (*)[STG_CH])smem;
    const int bh = blk & 7;                   // XCD-local chain
    const int b = bh >> 2, h = bh & 3;
    const int s = blk >> 3;                   // dv-slice 0..7
    const int lane = t;
    const int l31 = lane & 31, lhi = lane >> 5;

    f32x16 Sacc[8];
#pragma unroll
    for (int st = 0; st < 8; ++st)
#pragma unroll
      for (int e = 0; e < 16; ++e) Sacc[st][e] = 0.f;

    const unsigned short* ops = g_ops + (size_t)bh * 64 * OPS_CH;
    const int fo = lane * 8;
    const int utg = 24576 + s * 1024;         // global Ut-slice offset (shorts)

#define STAGE_CHUNK(SRC, DST)                                                              \
    {                                                                                      \
      const unsigned short* sp = (SRC);                                                    \
      unsigned short* dp = (DST);                                                          \
      _Pragma("unroll")                                                                    \
      for (int k = 0; k < 48; ++k)                                                         \
        GLL16(sp + (size_t)k * 512 + fo, dp + k * 512);                                    \
      _Pragma("unroll")                                                                    \
      for (int k = 0; k < 2; ++k) {                                                        \
        GLL16(sp + utg + (size_t)k * 512 + fo, dp + 24576 + k * 512);                      \
        GLL16(sp + 32768 + (size_t)k * 512 + fo, dp + 25600 + k * 512);                    \
      }                                                                                    \
    }

    STAGE_CHUNK(ops, &buf[0][0]);

    for (int n = 0; n < 64; ++n) {
      const int cur = n & 1;
      if (n == 0) asm volatile("s_waitcnt vmcnt(0)" ::: "memory");
      else        asm volatile("s_waitcnt vmcnt(16)" ::: "memory");

      if (n < 63) STAGE_CHUNK(ops + (size_t)(n + 1) * OPS_CH, &buf[cur ^ 1][0]);

      const unsigned short* Lb = &buf[cur][0];
      f32x16 wu0, wu1, wu2, wu3, ooA, ooB;
#pragma unroll
      for (int e = 0; e < 16; ++e) {
        wu0[e] = 0.f; wu1[e] = 0.f; wu2[e] = 0.f; wu3[e] = 0.f;
        ooA[e] = 0.f; ooB[e] = 0.f;
      }

      // ---- phase 1: wu = w@S (4 accumulation chains), oo = q@S ----
#pragma unroll
      for (int st = 0; st < 8; ++st) {
        short8v s0, s1;
        mkfrag(Sacc[st], s0, s1);
        short8v wa0 = *(const short8v*)&Lb[(st * 2 + 0) * 512 + fo];
        short8v wa1 = *(const short8v*)&Lb[(st * 2 + 1) * 512 + fo];
        short8v qa0 = *(const short8v*)&Lb[8192 + (st * 2 + 0) * 512 + fo];
        short8v qa1 = *(const short8v*)&Lb[8192 + (st * 2 + 1) * 512 + fo];
        if (st & 1) {
          wu2 = __builtin_amdgcn_mfma_f32_32x32x16_bf16(wa0, s0, wu2, 0, 0, 0);
          wu3 = __builtin_amdgcn_mfma_f32_32x32x16_bf16(wa1, s1, wu3, 0, 0, 0);
        } else {
          wu0 = __builtin_amdgcn_mfma_f32_32x32x16_bf16(wa0, s0, wu0, 0, 0, 0);
          wu1 = __builtin_amdgcn_mfma_f32_32x32x16_bf16(wa1, s1, wu1, 0, 0, 0);
        }
        ooA = __builtin_amdgcn_mfma_f32_32x32x16_bf16(qa0, s0, ooA, 0, 0, 0);
        ooB = __builtin_amdgcn_mfma_f32_32x32x16_bf16(qa1, s1, ooB, 0, 0, 0);
      }

      // ---- phase 2: u_t = u - wu -> B-frags ----
      f32x16 ut;
#pragma unroll
      for (int g = 0; g < 4; ++g) {
        uint2 uu = *(const uint2*)&Lb[24576 + ((g * 64) + lhi * 32 + l31) * 4];
        ut[4 * g + 0] = bf2f(uu.x & 0xffffu) - wu0[4 * g + 0] - wu1[4 * g + 0] - wu2[4 * g + 0] - wu3[4 * g + 0];
        ut[4 * g + 1] = bf2f(uu.x >> 16)     - wu0[4 * g + 1] - wu1[4 * g + 1] - wu2[4 * g + 1] - wu3[4 * g + 1];
        ut[4 * g + 2] = bf2f(uu.y & 0xffffu) - wu0[4 * g + 2] - wu1[4 * g + 2] - wu2[4 * g + 2] - wu3[4 * g + 2];
        ut[4 * g + 3] = bf2f(uu.y >> 16)     - wu0[4 * g + 3] - wu1[4 * g + 3] - wu2[4 * g + 3] - wu3[4 * g + 3];
      }
      short8v u0, u1;
      mkfrag(ut, u0, u1);

      // ---- phase 3: oo += attn @ u_t ; S += k^T @ u_t ----
      {
        short8v aa0 = *(const short8v*)&Lb[25600 + 0 * 512 + fo];
        short8v aa1 = *(const short8v*)&Lb[25600 + 1 * 512 + fo];
        ooA = __builtin_amdgcn_mfma_f32_32x32x16_bf16(aa0, u0, ooA, 0, 0, 0);
        ooB = __builtin_amdgcn_mfma_f32_32x32x16_bf16(aa1, u1, ooB, 0, 0, 0);
      }
#pragma unroll
      for (int st = 0; st < 8; ++st) {
        short8v ka0 = *(const short8v*)&Lb[16384 + (st * 2 + 0) * 512 + fo];
        short8v ka1 = *(const short8v*)&Lb[16384 + (st * 2 + 1) * 512 + fo];
        Sacc[st] = __builtin_amdgcn_mfma_f32_32x32x16_bf16(ka0, u0, Sacc[st], 0, 0, 0);
        Sacc[st] = __builtin_amdgcn_mfma_f32_32x32x16_bf16(ka1, u1, Sacc[st], 0, 0, 0);
      }

      // ---- write delta (fp32) — after the loads, so loads stay oldest ----
      size_t ob = ((size_t)(b * NL + n * 32)) * ND + h * 256 + s * 32 + l31;
#pragma unroll
      for (int e = 0; e < 16; ++e) {
        int row = (e & 3) + 8 * (e >> 2) + 4 * lhi;
        g_delta[ob + (size_t)row * ND] = ooA[e] + ooB[e];
      }
    }
#undef STAGE_CHUNK
  } else if (blk < 64 + 512) {
    // ---------------- fir_long path (K=64) ----------------
    float (*ft)[257] = (float (*)[257])smem;
    int fb_ = blk - 64;
    int cbk = fb_ & 3, lb = (fb_ >> 2) & 63, b = fb_ >> 8;
    int c = cbk * 256 + t;
    const float* fbp = firl + (size_t)cbk * 256 * 64;
#pragma unroll 4
    for (int i = 0; i < 64; ++i) {
      int j = t + i * 256;
      ft[j & 63][j >> 6] = fbp[j];
    }
    __syncthreads();
    float ff[64];
#pragma unroll
    for (int i = 0; i < 64; ++i) ff[i] = ft[i][t];
    float acc[32];
#pragma unroll
    for (int i = 0; i < 32; ++i) acc[i] = 0.f;
    const float* vb = g_v + (size_t)b * NL * ND + c;
    const int l0 = lb * 32;
#pragma unroll
    for (int d = 0; d < 95; ++d) {
      int lr = l0 - 63 + d;
      float vv = (lr >= 0) ? vb[(size_t)lr * ND] : 0.f;
      const int lo = (d > 63) ? (d - 63) : 0;
      const int hi = (d < 31) ? d : 31;
#pragma unroll
      for (int li = lo; li <= hi; ++li) acc[li] += ff[d - li] * vv;
    }
    float* ob = g_fl + ((size_t)(b * NL + l0)) * ND + c;
#pragma unroll
    for (int li = 0; li < 32; ++li) ob[(size_t)li * ND] = acc[li];
  } else if (blk < 64 + 512 + BLDSZ / 1024) {
    // ---------------- fir_short path (K=5), float4 ----------------
    int idx4 = (blk - 576) * 256 + t;
    int c4 = idx4 & 255;
    int bl = idx4 >> 8;
    int l = bl & (NL - 1);
    float fw[4][5];
#pragma unroll
    for (int j = 0; j < 4; ++j)
#pragma unroll
      for (int tap = 0; tap < 5; ++tap) fw[j][tap] = firs[(c4 * 4 + j) * 5 + tap];
    float4 acc = {0.f, 0.f, 0.f, 0.f};
    const float4* v4 = (const float4*)g_v;
#pragma unroll
    for (int tap = 0; tap < 5; ++tap) {
      int ls = l + tap - 4;
      if (ls >= 0) {
        float4 vv = v4[(size_t)(bl + tap - 4) * 256 + c4];
        acc.x += fw[0][tap] * vv.x; acc.y += fw[1][tap] * vv.y;
        acc.z += fw[2][tap] * vv.z; acc.w += fw[3][tap] * vv.w;
      }
    }
    ((float4*)g_fs)[(size_t)bl * 256 + c4] = acc;
  } else {
    // ---------------- xw1 GEMM path (sel=3), BK=64 swizzled ----------------
    unsigned short* As = (unsigned short*)smem;           // 128*64
    unsigned short* Bs = (unsigned short*)smem + 8192;
    int hb = blk - (64 + 512 + BLDSZ / 1024);
    const int m0 = (hb >> 3) * 128, n0 = (hb & 7) * 128;
    const int w = t >> 6, lane = t & 63, l31 = lane & 31, lhi = lane >> 5;
    const int wm = (w & 1) * 64, wn = (w >> 1) * 64;
    f32x16 acc[2][2];
    gemm128_core(g_xb, g_btw + (size_t)3 * 1024 * 1024, m0, n0, t, As, Bs, acc);
#pragma unroll
    for (int mt = 0; mt < 2; ++mt)
#pragma unroll
      for (int nt = 0; nt < 2; ++nt) {
        int col = n0 + wn + nt * 32 + l31;
#pragma unroll
        for (int e = 0; e < 16; ++e) {
          int row = m0 + wm + mt * 32 + (e & 3) + 8 * (e >> 2) + 4 * lhi;
          g_xw1[(size_t)row * 1024 + col] = acc[mt][nt][e];
        }
      }
  }
}

// ================= fused tail: stats -> wave-parallel gate -> mix+RMSNorm -> bf16 =================
__global__ __launch_bounds__(256) void tail_kernel(const float* __restrict__ W1,
                                                   const float* __restrict__ b1,
                                                   const float* __restrict__ W2,
                                                   const float* __restrict__ b2,
                                                   const float* __restrict__ log_temp,
                                                   const float* __restrict__ base_bias,
                                                   const float* __restrict__ crl,
                                                   const float* __restrict__ rms_w) {
  __shared__ float st[4][16];
  __shared__ float pl[4][4];
  int bl = blockIdx.x, t = threadIdx.x;
  int h = t >> 6, lane = t & 63;

  // ---- stats (wave h handles head h, loops branches) ----
  {
    size_t base = (size_t)bl * ND + h * 256 + lane * 4;
#pragma unroll
    for (int br = 0; br < 4; ++br) {
      const float* p = (br == 0) ? g_fs : (br == 1) ? g_fl : (br == 2) ? g_delta : g_v;
      float4 x4 = *(const float4*)&p[base];
      float s = x4.x + x4.y + x4.z + x4.w;
      float s2 = x4.x * x4.x + x4.y * x4.y + x4.z * x4.z + x4.w * x4.w;
      float sa = fabsf(x4.x) + fabsf(x4.y) + fabsf(x4.z) + fabsf(x4.w);
#pragma unroll
      for (int off = 32; off; off >>= 1) {
        s += __shfl_xor(s, off);
        s2 += __shfl_xor(s2, off);
        sa += __shfl_xor(sa, off);
      }
      if (lane == 0) {
        float mean = s * (1.f / 256.f);
        st[h][br * 4 + 0] = mean;
        st[h][br * 4 + 1] = s2 * (1.f / 256.f) - mean * mean;
        st[h][br * 4 + 2] = sa * (1.f / 256.f);
        st[h][br * 4 + 3] = sqrtf(s2);
      }
    }
  }
  __syncthreads();

  // ---- gate MLP: wave h computes head h in full (lane-strided j sweep) ----
  {
    const float* W1s = W1 + 1024 * 1024;
    float sv[16];
#pragma unroll
    for (int s = 0; s < 16; ++s) sv[s] = st[h][s];
    float a0 = 0.f, a1 = 0.f, a2 = 0.f, a3 = 0.f;
    for (int j = lane; j < 1024; j += 64) {
      float val = g_xw1[(size_t)bl * 1024 + j] + b1[j];
#pragma unroll
      for (int s = 0; s < 16; ++s) val += sv[s] * W1s[s * 1024 + j];
      float gg = 0.5f * val * (1.f + erff(val * 0.70710678118654752f));
      float4 w2 = *(const float4*)&W2[j * 4];
      a0 += gg * w2.x; a1 += gg * w2.y; a2 += gg * w2.z; a3 += gg * w2.w;
    }
#pragma unroll
    for (int off = 32; off; off >>= 1) {
      a0 += __shfl_xor(a0, off); a1 += __shfl_xor(a1, off);
      a2 += __shfl_xor(a2, off); a3 += __shfl_xor(a3, off);
    }
    if (lane == 0) {
      float lg[4] = {a0 + b2[0] + base_bias[h * 4 + 0], a1 + b2[1] + base_bias[h * 4 + 1],
                     a2 + b2[2] + base_bias[h * 4 + 2], a3 + b2[3] + base_bias[h * 4 + 3]};
      float lt = log_temp[h];
      float sp = (lt > 20.f) ? lt : log1pf(expf(lt));
      float inv = 1.f / (sp + 1e-4f);
      float z0 = lg[0] * inv, z1 = lg[1] * inv, z2 = lg[2] * inv, z3 = lg[3] * inv;
      float mx = fmaxf(fmaxf(z0, z1), fmaxf(z2, z3));
      float e0 = expf(z0 - mx), e1 = expf(z1 - mx), e2 = expf(z2 - mx), e3 = expf(z3 - mx);
      float si = 1.f / (e0 + e1 + e2 + e3);
      float p0 = e0 * si, p1 = e1 * si, p2 = e2 * si, p3 = e3 * si;
      p0 = fmaxf(p0, 0.05f); p1 = fmaxf(p1, 0.05f);
      float s2i = 1.f / (p0 + p1 + p2 + p3);
      p0 *= s2i; p1 *= s2i; p2 *= s2i; p3 *= s2i;
      p0 += 0.5f * sigmoidf(crl[h]);   // fold conv-residual into f_short coeff
      pl[h][0] = p0; pl[h][1] = p1; pl[h][2] = p2; pl[h][3] = p3;
    }
  }
  __syncthreads();

  // ---- mix + RMSNorm -> bf16 ----
  float p0 = pl[h][0], p1 = pl[h][1], p2 = pl[h][2], p3 = pl[h][3];
  size_t base = (size_t)bl * ND + h * 256 + lane * 4;
  float4 a = *(const float4*)&g_fs[base];
  float4 bb = *(const float4*)&g_fl[base];
  float4 c = *(const float4*)&g_delta[base];
  float4 d = *(const float4*)&g_v[base];
  float o0 = p0 * a.x + p1 * bb.x + p2 * c.x + p3 * d.x;
  float o1 = p0 * a.y + p1 * bb.y + p2 * c.y + p3 * d.y;
  float o2 = p0 * a.z + p1 * bb.z + p2 * c.z + p3 * d.z;
  float o3 = p0 * a.w + p1 * bb.w + p2 * c.w + p3 * d.w;
  float s2 = o0 * o0 + o1 * o1 + o2 * o2 + o3 * o3;
#pragma unroll
  for (int off = 32; off; off >>= 1) s2 += __shfl_xor(s2, off);
  float rms = rsqrtf(s2 * (1.f / 256.f) + 1e-5f);
  float4 w4 = *(const float4*)&rms_w[lane * 4];
  uint2 pw;
  pw.x = packbf(o0 * rms * w4.x, o1 * rms * w4.y);
  pw.y = packbf(o2 * rms * w4.z, o3 * rms * w4.w);
  *(uint2*)&g_omixb[base] = pw;
}

extern "C" void kernel_launch(void* const* d_in, const int* in_sizes, int n_in,
                              void* d_out, int out_size, void* d_ws, size_t ws_size,
                              hipStream_t stream) {
  const float* x = (const float*)d_in[0];
  const float* Wq = (const float*)d_in[1];
  const float* Wk = (const float*)d_in[2];
  const float* Wv = (const float*)d_in[3];
  const float* Wb = (const float*)d_in[4];
  const float* cq = (const float*)d_in[5];
  const float* ck = (const float*)d_in[6];
  const float* cv = (const float*)d_in[7];
  const float* firl = (const float*)d_in[8];
  const float* firs = (const float*)d_in[9];
  const float* W1 = (const float*)d_in[10];
  const float* b1 = (const float*)d_in[11];
  const float* W2 = (const float*)d_in[12];
  const float* b2 = (const float*)d_in[13];
  const float* ltp = (const float*)d_in[14];
  const float* bbs = (const float*)d_in[15];
  const float* crl = (const float*)d_in[16];
  const float* rw = (const float*)d_in[17];
  const float* Wo = (const float*)d_in[18];
  float* out = (float*)d_out;

  dim3 blk(256);
  pack_all_kernel<<<2048 + 5 * 256 + NBL, blk, 0, stream>>>(x, Wq, Wk, Wv, W1, Wo, Wb);
  qkv_gemm_kernel<<<768, blk, 0, stream>>>();
  delta_prep_kernel<<<NB * NH * NCHK, blk, 0, stream>>>(cq, ck, cv);
  scan_fir_kernel<<<64 + 512 + BLDSZ / 1024 + 256, blk, 0, stream>>>(firl, firs);
  tail_kernel<<<NBL, blk, 0, stream>>>(W1, b1, W2, b2, ltp, bbs, crl, rw);
  hgemm_out_kernel<<<256, blk, 0, stream>>>(out);
}

// Round 20
// 373.511 us; speedup vs baseline: 1.0687x; 1.0687x over previous
//
#include <hip/hip_runtime.h>
#include <math.h>

// Problem constants
constexpr int NB = 2, NL = 2048, ND = 1024, NH = 4;
constexpr int NCHK = 64;            // L / 32
constexpr int NBL = NB * NL;        // 4096
#define BLDSZ (NB * NL * ND)        // 4194304

// per-chunk packed operand file (shorts): [W 8192 | Q 8192 | Kt 8192 | Ut 8192 | At 1024 | pad]
constexpr int OPS_CH = 36864;       // shorts = 72 KB
// staged subset per scan wave: W 16 | Q 16 | Kt 16 | Ut-slice 2 | At 2 = 52 KB
constexpr int STG_CH = 26624;       // shorts = 52 KB

// ---- static device scratch ----
__device__ float g_v[BLDSZ];
__device__ float g_delta[BLDSZ];  // (B,L,H,DV)
__device__ float g_fs[BLDSZ];
__device__ float g_fl[BLDSZ];
__device__ float g_xw1[BLDSZ];    // x @ W1[:1024,:]
__device__ float g_beta[NBL * NH];
__device__ unsigned short g_qlb[BLDSZ];   // qkv GEMM outputs, bf16 (pre-conv)
__device__ unsigned short g_klb[BLDSZ];
__device__ unsigned short g_vlb[BLDSZ];
__device__ unsigned short g_ops[(size_t)8 * 64 * OPS_CH];  // 37.7 MB
__device__ unsigned short g_xb[BLDSZ];                      // x bf16
__device__ unsigned short g_omixb[BLDSZ];                   // mixed output bf16
__device__ unsigned short g_btw[5 * 1024 * 1024];           // 5 weights, [n][k] bf16

__device__ __forceinline__ float sigmoidf(float x) { return 1.f / (1.f + expf(-x)); }

__device__ __forceinline__ unsigned short f2bf(float f) {
  union { float f; unsigned int u; } v; v.f = f;
  unsigned int r = v.u + 0x7FFFu + ((v.u >> 16) & 1u);   // RNE
  return (unsigned short)(r >> 16);
}
__device__ __forceinline__ float bf2f(unsigned int bits16) {
  union { unsigned int u; float f; } v; v.u = bits16 << 16; return v.f;
}
__device__ __forceinline__ unsigned int packbf(float a, float b) {
  return (unsigned int)f2bf(a) | ((unsigned int)f2bf(b) << 16);
}

typedef __attribute__((ext_vector_type(8))) short short8v;   // 8 bf16 (4 VGPR)
typedef __attribute__((ext_vector_type(16))) float f32x16;   // MFMA 32x32 accum

__device__ __forceinline__ unsigned int cvtpk(float lo, float hi) {
  unsigned int r;
  asm("v_cvt_pk_bf16_f32 %0, %1, %2" : "=v"(r) : "v"(lo), "v"(hi));
  return r;
}

// C-layout f32x16 (col=l31, row=(e&3)+8*(e>>2)+4*lhi) -> two K-slice B-frags
__device__ __forceinline__ void mkfrag(const f32x16 v, short8v& fb0, short8v& fb1) {
  unsigned int P0 = cvtpk(v[0], v[1]),   P1 = cvtpk(v[2], v[3]);
  unsigned int P2 = cvtpk(v[4], v[5]),   P3 = cvtpk(v[6], v[7]);
  unsigned int P4 = cvtpk(v[8], v[9]),   P5 = cvtpk(v[10], v[11]);
  unsigned int P6 = cvtpk(v[12], v[13]), P7 = cvtpk(v[14], v[15]);
  asm("v_permlane32_swap_b32 %0, %1" : "+v"(P0), "+v"(P2));
  asm("v_permlane32_swap_b32 %0, %1" : "+v"(P1), "+v"(P3));
  asm("v_permlane32_swap_b32 %0, %1" : "+v"(P4), "+v"(P6));
  asm("v_permlane32_swap_b32 %0, %1" : "+v"(P5), "+v"(P7));
  unsigned int f0[4] = {P0, P1, P2, P3}, f1[4] = {P4, P5, P6, P7};
  fb0 = *(short8v*)f0; fb1 = *(short8v*)f1;
}

#define GLL16(SRC, DST)                                                                    \
  __builtin_amdgcn_global_load_lds(                                                        \
      (const __attribute__((address_space(1))) unsigned int*)(SRC),                        \
      (__attribute__((address_space(3))) unsigned int*)(DST), 16, 0, 0)

// ---- 128x128 / BK=64 GEMM core: both-sides row-XOR swizzle ----
__device__ __forceinline__ void gemm128_core(const unsigned short* __restrict__ A,
                                             const unsigned short* __restrict__ Bt,
                                             int m0, int n0, int t,
                                             unsigned short* As, unsigned short* Bs,
                                             f32x16 acc[2][2]) {
  const int w = t >> 6, lane = t & 63, l31 = lane & 31, lhi = lane >> 5;
  const int wm = (w & 1) * 64, wn = (w >> 1) * 64;
#pragma unroll
  for (int mt = 0; mt < 2; ++mt)
#pragma unroll
    for (int nt = 0; nt < 2; ++nt)
#pragma unroll
      for (int e = 0; e < 16; ++e) acc[mt][nt][e] = 0.f;

  for (int k0 = 0; k0 < 1024; k0 += 64) {
#pragma unroll
    for (int i = 0; i < 4; ++i) {
      int sl = i * 4 + w;
      int srow = sl * 8 + (lane >> 3);
      int gc = (((lane & 7) ^ (srow & 7))) * 8;
      GLL16(A + (size_t)(m0 + srow) * 1024 + k0 + gc, &As[sl * 512]);
      GLL16(Bt + (size_t)(n0 + srow) * 1024 + k0 + gc, &Bs[sl * 512]);
    }
    __syncthreads();
#pragma unroll
    for (int ksl = 0; ksl < 4; ++ksl) {
      int kb = ksl * 2 + lhi;
      short8v af[2], bf[2];
#pragma unroll
      for (int mt = 0; mt < 2; ++mt) {
        int row = wm + mt * 32 + l31;
        af[mt] = *(const short8v*)&As[row * 64 + ((kb ^ (row & 7)) * 8)];
      }
#pragma unroll
      for (int nt = 0; nt < 2; ++nt) {
        int row = wn + nt * 32 + l31;
        bf[nt] = *(const short8v*)&Bs[row * 64 + ((kb ^ (row & 7)) * 8)];
      }
#pragma unroll
      for (int mt = 0; mt < 2; ++mt)
#pragma unroll
        for (int nt = 0; nt < 2; ++nt)
          acc[mt][nt] = __builtin_amdgcn_mfma_f32_32x32x16_bf16(af[mt], bf[nt], acc[mt][nt], 0, 0, 0);
    }
    __syncthreads();
  }
}

// ================= pack_all: x->bf16 (0-2047) + 5 weights (2048-3327) + beta (3328-7423) =================
__global__ __launch_bounds__(256) void pack_all_kernel(const float* __restrict__ x,
                                                       const float* __restrict__ Wq,
                                                       const float* __restrict__ Wk,
                                                       const float* __restrict__ Wv,
                                                       const float* __restrict__ W1,
                                                       const float* __restrict__ Wo,
                                                       const float* __restrict__ Wb) {
  __shared__ float tile[64][65];
  int blk = blockIdx.x, t = threadIdx.x;
  if (blk < 2048) {
    int i8 = blk * 256 + t;
    const float* p = x + (size_t)i8 * 8;
    float4 a = *(const float4*)p;
    float4 b = *(const float4*)(p + 4);
    uint4 v;
    v.x = packbf(a.x, a.y); v.y = packbf(a.z, a.w);
    v.z = packbf(b.x, b.y); v.w = packbf(b.z, b.w);
    *(uint4*)&g_xb[(size_t)i8 * 8] = v;
    return;
  }
  if (blk < 3328) {
    int sel = (blk - 2048) >> 8, wb = (blk - 2048) & 255;
    const float* W = (sel == 0) ? Wq : (sel == 1) ? Wk : (sel == 2) ? Wv : (sel == 3) ? W1 : Wo;
    int bx = wb & 15, by = wb >> 4;
    int n0 = bx * 64, k0 = by * 64;
#pragma unroll
    for (int i = 0; i < 4; ++i) {
      int id = t + i * 256;
      int r = id >> 4, c4 = (id & 15) * 4;
      float4 v = *(const float4*)&W[(size_t)(k0 + r) * 1024 + n0 + c4];
      tile[r][c4 + 0] = v.x; tile[r][c4 + 1] = v.y; tile[r][c4 + 2] = v.z; tile[r][c4 + 3] = v.w;
    }
    __syncthreads();
    unsigned int* out = (unsigned int*)g_btw + (size_t)sel * 524288;
#pragma unroll
    for (int i = 0; i < 8; ++i) {
      int id = t + i * 256;
      int nn = id >> 5, ku = id & 31;
      out[(size_t)(n0 + nn) * 512 + (k0 >> 1) + ku] = packbf(tile[2 * ku][nn], tile[2 * ku + 1][nn]);
    }
    return;
  }
  // beta = sigmoid(x @ Wb)
  int bl = blk - 3328;
  int h = t >> 6, lane = t & 63;
  const float* xr = x + (size_t)bl * ND;
  float acc = 0.f;
  for (int d = lane; d < ND; d += 64) acc += xr[d] * Wb[d * 4 + h];
#pragma unroll
  for (int off = 32; off; off >>= 1) acc += __shfl_xor(acc, off);
  if (lane == 0) g_beta[bl * 4 + h] = sigmoidf(acc);
}

// ================= QKV GEMM: 3 GEMMs in one launch (grid 768), XCD-swizzled tiles =================
__global__ __launch_bounds__(256) void qkv_gemm_kernel() {
  __shared__ unsigned short As[128 * 64];
  __shared__ unsigned short Bs[128 * 64];
  const int sel = blockIdx.x >> 8;
  const int hb0 = blockIdx.x & 255;
  const int hb = (hb0 & 7) * 32 + (hb0 >> 3);    // XCD-contiguous by-ranges
  const unsigned short* Bt = g_btw + (size_t)sel * 1024 * 1024;
  unsigned short* C = (sel == 0) ? g_qlb : (sel == 1) ? g_klb : g_vlb;
  const int m0 = (hb >> 3) * 128, n0 = (hb & 7) * 128;
  const int t = threadIdx.x;
  const int w = t >> 6, lane = t & 63, l31 = lane & 31, lhi = lane >> 5;
  const int wm = (w & 1) * 64, wn = (w >> 1) * 64;
  f32x16 acc[2][2];
  gemm128_core(g_xb, Bt, m0, n0, t, As, Bs, acc);
#pragma unroll
  for (int mt = 0; mt < 2; ++mt)
#pragma unroll
    for (int nt = 0; nt < 2; ++nt) {
      int col = n0 + wn + nt * 32 + l31;
#pragma unroll
      for (int e = 0; e < 16; ++e) {
        int row = m0 + wm + mt * 32 + (e & 3) + 8 * (e >> 2) + 4 * lhi;
        C[(size_t)row * 1024 + col] = f2bf(acc[mt][nt][e]);
      }
    }
}

// ================= final GEMM: out = omixb @ Wo^T (BK=64 swizzled, XCD tiles) =================
__global__ __launch_bounds__(256) void hgemm_out_kernel(float* __restrict__ Cext) {
  __shared__ unsigned short As[128 * 64];
  __shared__ unsigned short Bs[128 * 64];
  const int hb = (blockIdx.x & 7) * 32 + (blockIdx.x >> 3);
  const int m0 = (hb >> 3) * 128, n0 = (hb & 7) * 128;
  const int t = threadIdx.x;
  const int w = t >> 6, lane = t & 63, l31 = lane & 31, lhi = lane >> 5;
  const int wm = (w & 1) * 64, wn = (w >> 1) * 64;
  f32x16 acc[2][2];
  gemm128_core(g_omixb, g_btw + (size_t)4 * 1024 * 1024, m0, n0, t, As, Bs, acc);
#pragma unroll
  for (int mt = 0; mt < 2; ++mt)
#pragma unroll
    for (int nt = 0; nt < 2; ++nt) {
      int col = n0 + wn + nt * 32 + l31;
#pragma unroll
      for (int e = 0; e < 16; ++e) {
        int row = m0 + wm + mt * 32 + (e & 3) + 8 * (e >> 2) + 4 * lhi;
        Cext[(size_t)row * 1024 + col] = acc[mt][nt][e];
      }
    }
}

// ================= delta-rule chunk prep: fused q/k/v conv+silu, MFMA attn/A, fast T-inverse =================
__global__ __launch_bounds__(256) void delta_prep_kernel(const float* __restrict__ cq,
                                                         const float* __restrict__ ck,
                                                         const float* __restrict__ cv) {
  __shared__ float X[32][260];
  __shared__ float Y[32][260];
  __shared__ float Am[32][33];
  __shared__ float Tm[32][33];
  __shared__ float bet[32];
  int blk = blockIdx.x;                  // cblk = (b*4+h)*64 + n
  int n = blk & 63, h = (blk >> 6) & 3, b = blk >> 8;
  int t = threadIdx.x;
  size_t rowbase = (size_t)(b * NL + n * 32);
  size_t obase = (size_t)blk * OPS_CH;
  const int st_ = t >> 5, j_ = (t >> 4) & 1, lh_ = (t >> 3) & 1, e_ = t & 7;
  const int l31_ = t & 31;

  float vv[32];   // v (post conv+silu) for this thread's column, rows 0..31

  // ---- fused causal conv(K=4)+SiLU for q,k,v from bf16 GEMM outputs; thread t owns head-col t ----
  {
    const int hcol = h * 256 + t;
    const unsigned short* qp = g_qlb + hcol;
    const unsigned short* kp = g_klb + hcol;
    const unsigned short* vp = g_vlb + hcol;
    float wq0 = cq[hcol * 4 + 0], wq1 = cq[hcol * 4 + 1], wq2 = cq[hcol * 4 + 2], wq3 = cq[hcol * 4 + 3];
    float wk0 = ck[hcol * 4 + 0], wk1 = ck[hcol * 4 + 1], wk2 = ck[hcol * 4 + 2], wk3 = ck[hcol * 4 + 3];
    float wv0 = cv[hcol * 4 + 0], wv1 = cv[hcol * 4 + 1], wv2 = cv[hcol * 4 + 2], wv3 = cv[hcol * 4 + 3];
    float qa = 0.f, qb_ = 0.f, qc = 0.f, ka = 0.f, kb_ = 0.f, kc = 0.f;
    float va = 0.f, vb_ = 0.f, vc = 0.f;
    if (n > 0) {
      qa = bf2f(qp[(rowbase - 3) * 1024]); qb_ = bf2f(qp[(rowbase - 2) * 1024]); qc = bf2f(qp[(rowbase - 1) * 1024]);
      ka = bf2f(kp[(rowbase - 3) * 1024]); kb_ = bf2f(kp[(rowbase - 2) * 1024]); kc = bf2f(kp[(rowbase - 1) * 1024]);
      va = bf2f(vp[(rowbase - 3) * 1024]); vb_ = bf2f(vp[(rowbase - 2) * 1024]); vc = bf2f(vp[(rowbase - 1) * 1024]);
    }
#pragma unroll 4
    for (int r = 0; r < 32; ++r) {
      float qd = bf2f(qp[(rowbase + r) * 1024]);
      float kd = bf2f(kp[(rowbase + r) * 1024]);
      float vd = bf2f(vp[(rowbase + r) * 1024]);
      float aq = wq3 * qd + wq2 * qc + wq1 * qb_ + wq0 * qa;
      float ak = wk3 * kd + wk2 * kc + wk1 * kb_ + wk0 * ka;
      float av = wv3 * vd + wv2 * vc + wv1 * vb_ + wv0 * va;
      X[r][t] = aq * sigmoidf(aq);
      Y[r][t] = ak * sigmoidf(ak);
      float vo = av * sigmoidf(av);
      vv[r] = vo;
      g_v[(rowbase + r) * 1024 + hcol] = vo;
      qa = qb_; qb_ = qc; qc = qd;
      ka = kb_; kb_ = kc; kc = kd;
      va = vb_; vb_ = vc; vc = vd;
    }
  }
  if (t < 32) bet[t] = g_beta[(rowbase + t) * 4 + h];
  __syncthreads();

  // row l2norm of q,k
  {
    int wv_ = t >> 6, lane = t & 63;
    int r = wv_ * 8 + (lane >> 3), sub = lane & 7;
    float sq = 0.f, sk = 0.f;
#pragma unroll
    for (int m4 = 0; m4 < 8; ++m4) {
      float4 a = *(const float4*)&X[r][sub * 32 + m4 * 4];
      float4 bb = *(const float4*)&Y[r][sub * 32 + m4 * 4];
      sq += a.x * a.x + a.y * a.y + a.z * a.z + a.w * a.w;
      sk += bb.x * bb.x + bb.y * bb.y + bb.z * bb.z + bb.w * bb.w;
    }
    sq += __shfl_xor(sq, 1); sq += __shfl_xor(sq, 2); sq += __shfl_xor(sq, 4);
    sk += __shfl_xor(sk, 1); sk += __shfl_xor(sk, 2); sk += __shfl_xor(sk, 4);
    float rq = rsqrtf(sq + 1e-6f), rk = rsqrtf(sk + 1e-6f);
#pragma unroll
    for (int m4 = 0; m4 < 8; ++m4) {
      float4 a = *(const float4*)&X[r][sub * 32 + m4 * 4];
      a.x *= rq; a.y *= rq; a.z *= rq; a.w *= rq;
      *(float4*)&X[r][sub * 32 + m4 * 4] = a;
      float4 bb = *(const float4*)&Y[r][sub * 32 + m4 * 4];
      bb.x *= rk; bb.y *= rk; bb.z *= rk; bb.w *= rk;
      *(float4*)&Y[r][sub * 32 + m4 * 4] = bb;
    }
  }
  __syncthreads();

  // attn = incl_lower(qn kn^T) via MFMA (wave 0) -> At region
  if (t < 64) {
    const int al = t & 31, ah = t >> 5;
    f32x16 Cat;
#pragma unroll
    for (int e = 0; e < 16; ++e) Cat[e] = 0.f;
#pragma unroll
    for (int st = 0; st < 16; ++st) {
      int kb = st * 16 + ah * 8;
      float4 a0 = *(const float4*)&X[al][kb], a1 = *(const float4*)&X[al][kb + 4];
      float4 b0 = *(const float4*)&Y[al][kb], b1 = *(const float4*)&Y[al][kb + 4];
      unsigned int af[4] = {cvtpk(a0.x, a0.y), cvtpk(a0.z, a0.w), cvtpk(a1.x, a1.y), cvtpk(a1.z, a1.w)};
      unsigned int bf_[4] = {cvtpk(b0.x, b0.y), cvtpk(b0.z, b0.w), cvtpk(b1.x, b1.y), cvtpk(b1.z, b1.w)};
      Cat = __builtin_amdgcn_mfma_f32_32x32x16_bf16(*(short8v*)af, *(short8v*)bf_, Cat, 0, 0, 0);
    }
#pragma unroll
    for (int e = 0; e < 16; ++e) {
      int row = (e & 3) + 8 * (e >> 2) + 4 * ah, col = al;
      float v = (col <= row) ? Cat[e] : 0.f;
      g_ops[obase + 32768 + (size_t)(((col >> 4) * 64) + ((col >> 3) & 1) * 32 + row) * 8 + (col & 7)] = f2bf(v);
    }
  }

  // qn -> Q region; kn -> Kt region
  {
    size_t qb = obase + 8192 + (size_t)(((st_ * 2 + j_) * 64) + lh_ * 32) * 8 + e_;
#pragma unroll 8
    for (int r = 0; r < 32; ++r)
      g_ops[qb + r * 8] = f2bf(X[r][t]);
#pragma unroll
    for (int j = 0; j < 2; ++j)
#pragma unroll
      for (int lh = 0; lh < 2; ++lh) {
        int kr0 = j * 16 + lh * 8;
        uint4 v;
        v.x = packbf(Y[kr0 + 0][t], Y[kr0 + 1][t]);
        v.y = packbf(Y[kr0 + 2][t], Y[kr0 + 3][t]);
        v.z = packbf(Y[kr0 + 4][t], Y[kr0 + 5][t]);
        v.w = packbf(Y[kr0 + 6][t], Y[kr0 + 7][t]);
        *(uint4*)&g_ops[obase + 16384 + (size_t)(((st_ * 2 + j) * 64) + lh * 32 + l31_) * 8] = v;
      }
  }
  __syncthreads();

  // X <- k_beta
#pragma unroll
  for (int i = 0; i < 8; ++i) {
    int j = t + i * 256;
    int r = j >> 6, d4 = (j & 63) << 2;
    float be = bet[r];
    float4 bb = *(const float4*)&Y[r][d4];
    bb.x *= be; bb.y *= be; bb.z *= be; bb.w *= be;
    *(float4*)&X[r][d4] = bb;
  }
  __syncthreads();

  // A = strict_lower(kb kn^T) via MFMA (wave 0) -> Am (fp32 LDS, lower only)
  if (t < 64) {
    const int al = t & 31, ah = t >> 5;
    f32x16 Cam;
#pragma unroll
    for (int e = 0; e < 16; ++e) Cam[e] = 0.f;
#pragma unroll
    for (int st = 0; st < 16; ++st) {
      int kb = st * 16 + ah * 8;
      float4 a0 = *(const float4*)&X[al][kb], a1 = *(const float4*)&X[al][kb + 4];
      float4 b0 = *(const float4*)&Y[al][kb], b1 = *(const float4*)&Y[al][kb + 4];
      unsigned int af[4] = {cvtpk(a0.x, a0.y), cvtpk(a0.z, a0.w), cvtpk(a1.x, a1.y), cvtpk(a1.z, a1.w)};
      unsigned int bf_[4] = {cvtpk(b0.x, b0.y), cvtpk(b0.z, b0.w), cvtpk(b1.x, b1.y), cvtpk(b1.z, b1.w)};
      Cam = __builtin_amdgcn_mfma_f32_32x32x16_bf16(*(short8v*)af, *(short8v*)bf_, Cam, 0, 0, 0);
    }
#pragma unroll
    for (int e = 0; e < 16; ++e) {
      int row = (e & 3) + 8 * (e >> 2) + 4 * ah, col = al;
      if (col < row) Am[row][col] = Cam[e];
    }
  }
  __syncthreads();

  // T = (I+A)^-1 forward substitution — fully-unrolled, exec-uniform
  if (t < 32) {
    const int j = t;
#pragma unroll
    for (int i = 0; i < 32; ++i) {
      float a = (i == j) ? 1.f : 0.f;
#pragma unroll
      for (int m = 0; m < i; ++m) {
        float p = Am[i][m] * Tm[m][j];
        a -= (m >= j) ? p : 0.f;
      }
      Tm[i][j] = a;
    }
  }
  __syncthreads();

  // w = T @ kb -> W region
  {
    float acc[32];
#pragma unroll
    for (int r = 0; r < 32; ++r) acc[r] = 0.f;
#pragma unroll
    for (int m = 0; m < 32; ++m) {
      float xv = X[m][t];
#pragma unroll
      for (int r = m; r < 32; ++r) acc[r] += Tm[r][m] * xv;
    }
    size_t wb = obase + (size_t)(((st_ * 2 + j_) * 64) + lh_ * 32) * 8 + e_;
#pragma unroll 8
    for (int r = 0; r < 32; ++r)
      g_ops[wb + r * 8] = f2bf(acc[r]);
  }
  // Y <- v*beta (from registers, no global read)
  __syncthreads();
#pragma unroll
  for (int r = 0; r < 32; ++r)
    Y[r][t] = vv[r] * bet[r];
  __syncthreads();

  // u = T @ vb -> Ut region
  {
    float acc[32];
#pragma unroll
    for (int r = 0; r < 32; ++r) acc[r] = 0.f;
#pragma unroll
    for (int m = 0; m < 32; ++m) {
      float yv = Y[m][t];
#pragma unroll
      for (int r = m; r < 32; ++r) acc[r] += Tm[r][m] * yv;
    }
    int q = t >> 5;
#pragma unroll
    for (int g = 0; g < 4; ++g)
#pragma unroll
      for (int lh = 0; lh < 2; ++lh) {
        int kr0 = 8 * g + 4 * lh;
        uint2 v;
        v.x = packbf(acc[kr0 + 0], acc[kr0 + 1]);
        v.y = packbf(acc[kr0 + 2], acc[kr0 + 3]);
        *(uint2*)&g_ops[obase + 24576 + (size_t)(((q * 4 + g) * 64) + lh * 32 + l31_) * 4] = v;
      }
  }
}

// ================= MEGA: scan (0-63) + fir_long (64-575) + fir_short (576-4671) + xw1 (4672-4927) =================
__global__ __launch_bounds__(256, 1) void scan_fir_kernel(const float* __restrict__ firl,
                                                          const float* __restrict__ firs) {
  __shared__ __align__(16) unsigned char smem[2 * STG_CH * 2];  // 104 KB
  const int blk = blockIdx.x;
  const int t = threadIdx.x;

  if (blk < 64) {
    if (t >= 64) return;   // scan path: wave 0 only, no barriers
    unsigned short (*buf)[STG_CH] = (unsigned short (*)[STG_CH])smem;
    const int bh = blk & 7;                   // XCD-local chain
    const int b = bh >> 2, h = bh & 3;
    const int s = blk >> 3;                   // dv-slice 0..7
    const int lane = t;
    const int l31 = lane & 31, lhi = lane >> 5;

    f32x16 Sacc[8];
#pragma unroll
    for (int st = 0; st < 8; ++st)
#pragma unroll
      for (int e = 0; e < 16; ++e) Sacc[st][e] = 0.f;

    const unsigned short* ops = g_ops + (size_t)bh * 64 * OPS_CH;
    const int fo = lane * 8;
    const int utg = 24576 + s * 1024;         // global Ut-slice offset (shorts)

#define STAGE_CHUNK(SRC, DST)                                                              \
    {                                                                                      \
      const unsigned short* sp = (SRC);                                                    \
      unsigned short* dp = (DST);                                                          \
      _Pragma("unroll")                                                                    \
      for (int k = 0; k < 48; ++k)                                                         \
        GLL16(sp + (size_t)k * 512 + fo, dp + k * 512);                                    \
      _Pragma("unroll")                                                                    \
      for (int k = 0; k < 2; ++k) {                                                        \
        GLL16(sp + utg + (size_t)k * 512 + fo, dp + 24576 + k * 512);                      \
        GLL16(sp + 32768 + (size_t)k * 512 + fo, dp + 25600 + k * 512);                    \
      }                                                                                    \
    }

    STAGE_CHUNK(ops, &buf[0][0]);

    for (int n = 0; n < 64; ++n) {
      const int cur = n & 1;
      // drain chunk-n's 52 loads (oldest); <=16 stores from step n-1 may remain
      if (n == 0) asm volatile("s_waitcnt vmcnt(0)" ::: "memory");
      else        asm volatile("s_waitcnt vmcnt(16)" ::: "memory");

      if (n < 63) STAGE_CHUNK(ops + (size_t)(n + 1) * OPS_CH, &buf[cur ^ 1][0]);

      const unsigned short* Lb = &buf[cur][0];
      f32x16 wuA, wuB, ooA, ooB;
#pragma unroll
      for (int e = 0; e < 16; ++e) { wuA[e] = 0.f; wuB[e] = 0.f; ooA[e] = 0.f; ooB[e] = 0.f; }

      // ---- phase 1: wu = w@S, oo = q@S ----
#pragma unroll
      for (int st = 0; st < 8; ++st) {
        short8v s0, s1;
        mkfrag(Sacc[st], s0, s1);
        short8v wa0 = *(const short8v*)&Lb[(st * 2 + 0) * 512 + fo];
        short8v wa1 = *(const short8v*)&Lb[(st * 2 + 1) * 512 + fo];
        short8v qa0 = *(const short8v*)&Lb[8192 + (st * 2 + 0) * 512 + fo];
        short8v qa1 = *(const short8v*)&Lb[8192 + (st * 2 + 1) * 512 + fo];
        wuA = __builtin_amdgcn_mfma_f32_32x32x16_bf16(wa0, s0, wuA, 0, 0, 0);
        wuB = __builtin_amdgcn_mfma_f32_32x32x16_bf16(wa1, s1, wuB, 0, 0, 0);
        ooA = __builtin_amdgcn_mfma_f32_32x32x16_bf16(qa0, s0, ooA, 0, 0, 0);
        ooB = __builtin_amdgcn_mfma_f32_32x32x16_bf16(qa1, s1, ooB, 0, 0, 0);
      }

      // ---- phase 2: u_t = u - wu -> B-frags ----
      f32x16 ut;
#pragma unroll
      for (int g = 0; g < 4; ++g) {
        uint2 uu = *(const uint2*)&Lb[24576 + ((g * 64) + lhi * 32 + l31) * 4];
        ut[4 * g + 0] = bf2f(uu.x & 0xffffu) - wuA[4 * g + 0] - wuB[4 * g + 0];
        ut[4 * g + 1] = bf2f(uu.x >> 16)     - wuA[4 * g + 1] - wuB[4 * g + 1];
        ut[4 * g + 2] = bf2f(uu.y & 0xffffu) - wuA[4 * g + 2] - wuB[4 * g + 2];
        ut[4 * g + 3] = bf2f(uu.y >> 16)     - wuA[4 * g + 3] - wuB[4 * g + 3];
      }
      short8v u0, u1;
      mkfrag(ut, u0, u1);

      // ---- phase 3: oo += attn @ u_t ; S += k^T @ u_t ----
      {
        short8v aa0 = *(const short8v*)&Lb[25600 + 0 * 512 + fo];
        short8v aa1 = *(const short8v*)&Lb[25600 + 1 * 512 + fo];
        ooA = __builtin_amdgcn_mfma_f32_32x32x16_bf16(aa0, u0, ooA, 0, 0, 0);
        ooB = __builtin_amdgcn_mfma_f32_32x32x16_bf16(aa1, u1, ooB, 0, 0, 0);
      }
#pragma unroll
      for (int st = 0; st < 8; ++st) {
        short8v ka0 = *(const short8v*)&Lb[16384 + (st * 2 + 0) * 512 + fo];
        short8v ka1 = *(const short8v*)&Lb[16384 + (st * 2 + 1) * 512 + fo];
        Sacc[st] = __builtin_amdgcn_mfma_f32_32x32x16_bf16(ka0, u0, Sacc[st], 0, 0, 0);
        Sacc[st] = __builtin_amdgcn_mfma_f32_32x32x16_bf16(ka1, u1, Sacc[st], 0, 0, 0);
      }

      // ---- write delta (fp32) — after the loads, so loads stay oldest ----
      size_t ob = ((size_t)(b * NL + n * 32)) * ND + h * 256 + s * 32 + l31;
#pragma unroll
      for (int e = 0; e < 16; ++e) {
        int row = (e & 3) + 8 * (e >> 2) + 4 * lhi;
        g_delta[ob + (size_t)row * ND] = ooA[e] + ooB[e];
      }
    }
#undef STAGE_CHUNK
  } else if (blk < 64 + 512) {
    // ---------------- fir_long path (K=64) ----------------
    float (*ft)[257] = (float (*)[257])smem;
    int fb_ = blk - 64;
    int cbk = fb_ & 3, lb = (fb_ >> 2) & 63, b = fb_ >> 8;
    int c = cbk * 256 + t;
    const float* fbp = firl + (size_t)cbk * 256 * 64;
#pragma unroll 4
    for (int i = 0; i < 64; ++i) {
      int j = t + i * 256;
      ft[j & 63][j >> 6] = fbp[j];
    }
    __syncthreads();
    float ff[64];
#pragma unroll
    for (int i = 0; i < 64; ++i) ff[i] = ft[i][t];
    float acc[32];
#pragma unroll
    for (int i = 0; i < 32; ++i) acc[i] = 0.f;
    const float* vb = g_v + (size_t)b * NL * ND + c;
    const int l0 = lb * 32;
#pragma unroll
    for (int d = 0; d < 95; ++d) {
      int lr = l0 - 63 + d;
      float vv = (lr >= 0) ? vb[(size_t)lr * ND] : 0.f;
      const int lo = (d > 63) ? (d - 63) : 0;
      const int hi = (d < 31) ? d : 31;
#pragma unroll
      for (int li = lo; li <= hi; ++li) acc[li] += ff[d - li] * vv;
    }
    float* ob = g_fl + ((size_t)(b * NL + l0)) * ND + c;
#pragma unroll
    for (int li = 0; li < 32; ++li) ob[(size_t)li * ND] = acc[li];
  } else if (blk < 64 + 512 + BLDSZ / 1024) {
    // ---------------- fir_short path (K=5), float4 ----------------
    int idx4 = (blk - 576) * 256 + t;
    int c4 = idx4 & 255;
    int bl = idx4 >> 8;
    int l = bl & (NL - 1);
    float fw[4][5];
#pragma unroll
    for (int j = 0; j < 4; ++j)
#pragma unroll
      for (int tap = 0; tap < 5; ++tap) fw[j][tap] = firs[(c4 * 4 + j) * 5 + tap];
    float4 acc = {0.f, 0.f, 0.f, 0.f};
    const float4* v4 = (const float4*)g_v;
#pragma unroll
    for (int tap = 0; tap < 5; ++tap) {
      int ls = l + tap - 4;
      if (ls >= 0) {
        float4 vv = v4[(size_t)(bl + tap - 4) * 256 + c4];
        acc.x += fw[0][tap] * vv.x; acc.y += fw[1][tap] * vv.y;
        acc.z += fw[2][tap] * vv.z; acc.w += fw[3][tap] * vv.w;
      }
    }
    ((float4*)g_fs)[(size_t)bl * 256 + c4] = acc;
  } else {
    // ---------------- xw1 GEMM path (sel=3), BK=64 swizzled ----------------
    unsigned short* As = (unsigned short*)smem;           // 128*64
    unsigned short* Bs = (unsigned short*)smem + 8192;
    int hb = blk - (64 + 512 + BLDSZ / 1024);
    const int m0 = (hb >> 3) * 128, n0 = (hb & 7) * 128;
    const int w = t >> 6, lane = t & 63, l31 = lane & 31, lhi = lane >> 5;
    const int wm = (w & 1) * 64, wn = (w >> 1) * 64;
    f32x16 acc[2][2];
    gemm128_core(g_xb, g_btw + (size_t)3 * 1024 * 1024, m0, n0, t, As, Bs, acc);
#pragma unroll
    for (int mt = 0; mt < 2; ++mt)
#pragma unroll
      for (int nt = 0; nt < 2; ++nt) {
        int col = n0 + wn + nt * 32 + l31;
#pragma unroll
        for (int e = 0; e < 16; ++e) {
          int row = m0 + wm + mt * 32 + (e & 3) + 8 * (e >> 2) + 4 * lhi;
          g_xw1[(size_t)row * 1024 + col] = acc[mt][nt][e];
        }
      }
  }
}

// ================= fused tail: stats -> wave-parallel gate -> mix+RMSNorm -> bf16 =================
__global__ __launch_bounds__(256) void tail_kernel(const float* __restrict__ W1,
                                                   const float* __restrict__ b1,
                                                   const float* __restrict__ W2,
                                                   const float* __restrict__ b2,
                                                   const float* __restrict__ log_temp,
                                                   const float* __restrict__ base_bias,
                                                   const float* __restrict__ crl,
                                                   const float* __restrict__ rms_w) {
  __shared__ float st[4][16];
  __shared__ float pl[4][4];
  int bl = blockIdx.x, t = threadIdx.x;
  int h = t >> 6, lane = t & 63;

  // ---- stats (wave h handles head h, loops branches) ----
  {
    size_t base = (size_t)bl * ND + h * 256 + lane * 4;
#pragma unroll
    for (int br = 0; br < 4; ++br) {
      const float* p = (br == 0) ? g_fs : (br == 1) ? g_fl : (br == 2) ? g_delta : g_v;
      float4 x4 = *(const float4*)&p[base];
      float s = x4.x + x4.y + x4.z + x4.w;
      float s2 = x4.x * x4.x + x4.y * x4.y + x4.z * x4.z + x4.w * x4.w;
      float sa = fabsf(x4.x) + fabsf(x4.y) + fabsf(x4.z) + fabsf(x4.w);
#pragma unroll
      for (int off = 32; off; off >>= 1) {
        s += __shfl_xor(s, off);
        s2 += __shfl_xor(s2, off);
        sa += __shfl_xor(sa, off);
      }
      if (lane == 0) {
        float mean = s * (1.f / 256.f);
        st[h][br * 4 + 0] = mean;
        st[h][br * 4 + 1] = s2 * (1.f / 256.f) - mean * mean;
        st[h][br * 4 + 2] = sa * (1.f / 256.f);
        st[h][br * 4 + 3] = sqrtf(s2);
      }
    }
  }
  __syncthreads();

  // ---- gate MLP: wave h computes head h in full (lane-strided j sweep) ----
  {
    const float* W1s = W1 + 1024 * 1024;
    float sv[16];
#pragma unroll
    for (int s = 0; s < 16; ++s) sv[s] = st[h][s];
    float a0 = 0.f, a1 = 0.f, a2 = 0.f, a3 = 0.f;
    for (int j = lane; j < 1024; j += 64) {
      float val = g_xw1[(size_t)bl * 1024 + j] + b1[j];
#pragma unroll
      for (int s = 0; s < 16; ++s) val += sv[s] * W1s[s * 1024 + j];
      float gg = 0.5f * val * (1.f + erff(val * 0.70710678118654752f));
      float4 w2 = *(const float4*)&W2[j * 4];
      a0 += gg * w2.x; a1 += gg * w2.y; a2 += gg * w2.z; a3 += gg * w2.w;
    }
#pragma unroll
    for (int off = 32; off; off >>= 1) {
      a0 += __shfl_xor(a0, off); a1 += __shfl_xor(a1, off);
      a2 += __shfl_xor(a2, off); a3 += __shfl_xor(a3, off);
    }
    if (lane == 0) {
      float lg[4] = {a0 + b2[0] + base_bias[h * 4 + 0], a1 + b2[1] + base_bias[h * 4 + 1],
                     a2 + b2[2] + base_bias[h * 4 + 2], a3 + b2[3] + base_bias[h * 4 + 3]};
      float lt = log_temp[h];
      float sp = (lt > 20.f) ? lt : log1pf(expf(lt));
      float inv = 1.f / (sp + 1e-4f);
      float z0 = lg[0] * inv, z1 = lg[1] * inv, z2 = lg[2] * inv, z3 = lg[3] * inv;
      float mx = fmaxf(fmaxf(z0, z1), fmaxf(z2, z3));
      float e0 = expf(z0 - mx), e1 = expf(z1 - mx), e2 = expf(z2 - mx), e3 = expf(z3 - mx);
      float si = 1.f / (e0 + e1 + e2 + e3);
      float p0 = e0 * si, p1 = e1 * si, p2 = e2 * si, p3 = e3 * si;
      p0 = fmaxf(p0, 0.05f); p1 = fmaxf(p1, 0.05f);
      float s2i = 1.f / (p0 + p1 + p2 + p3);
      p0 *= s2i; p1 *= s2i; p2 *= s2i; p3 *= s2i;
      p0 += 0.5f * sigmoidf(crl[h]);   // fold conv-residual into f_short coeff
      pl[h][0] = p0; pl[h][1] = p1; pl[h][2] = p2; pl[h][3] = p3;
    }
  }
  __syncthreads();

  // ---- mix + RMSNorm -> bf16 ----
  float p0 = pl[h][0], p1 = pl[h][1], p2 = pl[h][2], p3 = pl[h][3];
  size_t base = (size_t)bl * ND + h * 256 + lane * 4;
  float4 a = *(const float4*)&g_fs[base];
  float4 bb = *(const float4*)&g_fl[base];
  float4 c = *(const float4*)&g_delta[base];
  float4 d = *(const float4*)&g_v[base];
  float o0 = p0 * a.x + p1 * bb.x + p2 * c.x + p3 * d.x;
  float o1 = p0 * a.y + p1 * bb.y + p2 * c.y + p3 * d.y;
  float o2 = p0 * a.z + p1 * bb.z + p2 * c.z + p3 * d.z;
  float o3 = p0 * a.w + p1 * bb.w + p2 * c.w + p3 * d.w;
  float s2 = o0 * o0 + o1 * o1 + o2 * o2 + o3 * o3;
#pragma unroll
  for (int off = 32; off; off >>= 1) s2 += __shfl_xor(s2, off);
  float rms = rsqrtf(s2 * (1.f / 256.f) + 1e-5f);
  float4 w4 = *(const float4*)&rms_w[lane * 4];
  uint2 pw;
  pw.x = packbf(o0 * rms * w4.x, o1 * rms * w4.y);
  pw.y = packbf(o2 * rms * w4.z, o3 * rms * w4.w);
  *(uint2*)&g_omixb[base] = pw;
}

extern "C" void kernel_launch(void* const* d_in, const int* in_sizes, int n_in,
                              void* d_out, int out_size, void* d_ws, size_t ws_size,
                              hipStream_t stream) {
  const float* x = (const float*)d_in[0];
  const float* Wq = (const float*)d_in[1];
  const float* Wk = (const float*)d_in[2];
  const float* Wv = (const float*)d_in[3];
  const float* Wb = (const float*)d_in[4];
  const float* cq = (const float*)d_in[5];
  const float* ck = (const float*)d_in[6];
  const float* cv = (const float*)d_in[7];
  const float* firl = (const float*)d_in[8];
  const float* firs = (const float*)d_in[9];
  const float* W1 = (const float*)d_in[10];
  const float* b1 = (const float*)d_in[11];
  const float* W2 = (const float*)d_in[12];
  const float* b2 = (const float*)d_in[13];
  const float* ltp = (const float*)d_in[14];
  const float* bbs = (const float*)d_in[15];
  const float* crl = (const float*)d_in[16];
  const float* rw = (const float*)d_in[17];
  const float* Wo = (const float*)d_in[18];
  float* out = (float*)d_out;

  dim3 blk(256);
  pack_all_kernel<<<2048 + 5 * 256 + NBL, blk, 0, stream>>>(x, Wq, Wk, Wv, W1, Wo, Wb);
  qkv_gemm_kernel<<<768, blk, 0, stream>>>();
  delta_prep_kernel<<<NB * NH * NCHK, blk, 0, stream>>>(cq, ck, cv);
  scan_fir_kernel<<<64 + 512 + BLDSZ / 1024 + 256, blk, 0, stream>>>(firl, firs);
  tail_kernel<<<NBL, blk, 0, stream>>>(W1, b1, W2, b2, ltp, bbs, crl, rw);
  hgemm_out_kernel<<<256, blk, 0, stream>>>(out);
}